// Round 3
// baseline (206.917 us; speedup 1.0000x reference)
//
#include <hip/hip_runtime.h>

typedef unsigned short u16;
typedef _Float16 half_t;
typedef __attribute__((ext_vector_type(8))) _Float16 h8;
typedef __attribute__((ext_vector_type(2))) _Float16 h2v;
typedef __attribute__((ext_vector_type(4))) float f4;
typedef __attribute__((ext_vector_type(2))) float f2;

// fp32 -> fp16 with inf/NaN killing (fmaxf/fminf return the non-NaN operand).
__device__ __forceinline__ half_t to_h(float v) {
    v = fminf(fmaxf(v, -60000.f), 60000.f);
    return (half_t)v;
}

// ---------------- pack kernel: permute fp32 weights into MFMA-B fragment order (fp16) ----
// ws layout (half elements):
//   w1p: [0, 524288)          [kk=64][nt=16][lane=64][j=8]  <- w1[k=kk*32+(L>>4)*8+j][n=nt*16+(L&15)]
//   w2p: [524288, 557056)     [kk=8][nt=8][64][8]
//   swp: [557056, 622592)     [kk=16][nt=8][64][8]
//   cwp: [622592, 630912)     [p=k*13+ip][c=64][r=2] pre-paired conv weights
__global__ void pack_k(const float* __restrict__ w1, const float* __restrict__ w2,
                       const float* __restrict__ sw, const float* __restrict__ cw,
                       half_t* __restrict__ wsH) {
    int i = blockIdx.x * 256 + threadIdx.x;
    if (i < 524288) {
        int j = i & 7, L = (i >> 3) & 63, nt = (i >> 9) & 15, kk = i >> 13;
        int k = kk * 32 + ((L >> 4) << 3) + j, n = (nt << 4) + (L & 15);
        wsH[i] = to_h(w1[(k << 8) + n]);
    } else if (i < 557056) {
        int o = i - 524288;
        int j = o & 7, L = (o >> 3) & 63, nt = (o >> 9) & 7, kk = o >> 12;
        int k = kk * 32 + ((L >> 4) << 3) + j, n = (nt << 4) + (L & 15);
        wsH[i] = to_h(w2[(k << 7) + n]);
    } else if (i < 622592) {
        int o = i - 557056;
        int j = o & 7, L = (o >> 3) & 63, nt = (o >> 9) & 7, kk = o >> 12;
        int k = kk * 32 + ((L >> 4) << 3) + j, n = (nt << 4) + (L & 15);
        wsH[i] = to_h(sw[(k << 7) + n]);
    } else if (i < 630912) {
        int o = i - 622592;
        int r = o & 1, c = (o >> 1) & 63, p = o >> 7;
        int k = p / 13, ip = p - k * 13;
        wsH[i] = to_h(cw[(k * 26 + 2 * ip + r) * 64 + c]);
    }
}

// ---------------- main fused kernel ----------------
// block = 256 thr (4 waves), handles one b and 64 consecutive t.
#define XCS 72   // xcL row stride (halfs), 95 rows, frame f <-> t = t0-31+f
#define ALS 72   // aL row stride (halfs), 64 rows
#define Y1S 264  // y1L / hL row stride (halfs)
#define SLS 68   // sLf row stride (floats)
#define HLS 20   // hidL row stride (floats)

__global__ __launch_bounds__(256) void beat_main(
    const float* __restrict__ x,
    const float* __restrict__ conv_b,
    const float* __restrict__ se_w1, const float* __restrict__ se_b1,
    const float* __restrict__ se_w2, const float* __restrict__ se_b2,
    const float* __restrict__ b1, const float* __restrict__ b2,
    const float* __restrict__ sb,
    const float* __restrict__ wo, const float* __restrict__ bo,
    const half_t* __restrict__ w1p, const half_t* __restrict__ w2p,
    const half_t* __restrict__ swp, const half_t* __restrict__ cwp,
    float* __restrict__ out) {

    __shared__ __align__(16) char smem[59264];
    half_t* xcL  = (half_t*)(smem);            // 95*72*2 = 13680
    half_t* aL   = (half_t*)(smem + 13680);    // 64*72*2 = 9216  -> 22896
    char*   U    = smem + 23408;               // 33808-byte phase-union
    half_t* xLh  = (half_t*)U;                 // phase0: 99 rows * 28 halfs
    half_t* cwLh = (half_t*)(U + 5568);        // phase0: 8320 halfs
    float*  sLf  = (float*)U;                  // phase1: 64*68 floats
    float*  hidL = (float*)(U + 17408);        // phase1: 64*20 floats
    half_t* y1L  = (half_t*)U;                 // phase2/3: 64*264 halfs; phase5: hL
    float*  woL  = (float*)(smem + 57216);     // 512 floats

    const int tid = threadIdx.x;
    const int bi = blockIdx.x;
    const int b = bi >> 6;
    const int t0 = (bi & 63) << 6;
    const int lane = tid & 63, wv = tid >> 6;
    const int quad = lane >> 4, rl = lane & 15;

    // ---- phase 0a: stage x (fp16 pairs), conv weights, wo ----
    ((f2*)woL)[tid] = ((const f2*)wo)[tid];    // 512 floats
    for (int idx = tid; idx < 99 * 13; idx += 256) {
        int f2i = idx / 13, ip = idx - f2i * 13;
        int tx = t0 - 35 + f2i;
        h2v v;
        if (tx >= 0) {
            const float* xp = x + ((size_t)(b * 4096 + tx)) * 26 + 2 * ip;
            v[0] = to_h(xp[0]); v[1] = to_h(xp[1]);
        } else { v[0] = (_Float16)0.f; v[1] = (_Float16)0.f; }
        *(h2v*)(xLh + f2i * 28 + 2 * ip) = v;
    }
    for (int idx = tid; idx < 4160; idx += 256)
        ((unsigned int*)cwLh)[idx] = ((const unsigned int*)cwp)[idx];
    __syncthreads();

    // ---- phase 0b: causal conv (K=5, 26->64) + relu -> xcL (fp16) ----
    {
        int c = tid & 63, f0 = tid >> 6;
        h2v cwr[65];
        const h2v* cwp2 = (const h2v*)cwLh;
#pragma unroll
        for (int j = 0; j < 65; j++) cwr[j] = cwp2[j * 64 + c];
        float bias = conv_b[c];
        for (int f = f0; f < 95; f += 4) {
            int t = t0 - 31 + f;
            float r0 = 0.f;
            if (t >= 0) {
                h2v accp; accp[0] = (_Float16)0.f; accp[1] = (_Float16)0.f;
#pragma unroll
                for (int k = 0; k < 5; k++)
#pragma unroll
                    for (int ip = 0; ip < 13; ip++) {
                        h2v xp = *(const h2v*)(xLh + (f + k) * 28 + 2 * ip);
                        accp += xp * cwr[k * 13 + ip];
                    }
                r0 = fmaxf((float)accp[0] + (float)accp[1] + bias, 0.f);
            }
            xcL[f * XCS + c] = to_h(r0);
        }
    }
    __syncthreads();

    // ---- phase 1a: sliding window means s[m][c] (window of m = xcL rows m..m+31) ----
    {
        int c = tid & 63, mb = tid >> 6;
        float run = 0.f;
#pragma unroll 8
        for (int w = 0; w < 32; w++) run += (float)xcL[(mb + w) * XCS + c];
        sLf[mb * SLS + c] = run * (1.f / 32.f);
        for (int m = mb + 4; m < 64; m += 4) {
#pragma unroll
            for (int d = 0; d < 4; d++) {
                run += (float)xcL[(m + 28 + d) * XCS + c];
                run -= (float)xcL[(m - 4 + d) * XCS + c];
            }
            sLf[m * SLS + c] = run * (1.f / 32.f);
        }
    }
    __syncthreads();

    // ---- phase 1b: SE hidden = relu(s @ se_w1 + se_b1) ----
    {
        int m = tid >> 2, hh = (tid & 3) * 4;
        float acc[4];
#pragma unroll
        for (int j = 0; j < 4; j++) acc[j] = se_b1[hh + j];
        const f4* sw1v = (const f4*)se_w1;
        for (int c = 0; c < 64; c++) {
            float sv = sLf[m * SLS + c];
            f4 wq = sw1v[c * 4 + (tid & 3)];
            acc[0] += sv * wq[0]; acc[1] += sv * wq[1];
            acc[2] += sv * wq[2]; acc[3] += sv * wq[3];
        }
#pragma unroll
        for (int j = 0; j < 4; j++) hidL[m * HLS + hh + j] = fmaxf(acc[j], 0.f);
    }
    __syncthreads();

    // ---- phase 1c: a = sigmoid(hidden @ se_w2 + se_b2) -> aL (fp16) ----
    {
        int m = tid >> 2, c0 = (tid & 3) * 16;
        float av[16];
#pragma unroll
        for (int j = 0; j < 16; j++) av[j] = se_b2[c0 + j];
        for (int h = 0; h < 16; h++) {
            float hv = hidL[m * HLS + h];
            const f4* w2v = (const f4*)(se_w2 + h * 64 + c0);
#pragma unroll
            for (int q = 0; q < 4; q++) {
                f4 wq = w2v[q];
#pragma unroll
                for (int j = 0; j < 4; j++) av[q * 4 + j] += hv * wq[j];
            }
        }
#pragma unroll
        for (int j = 0; j < 16; j++) {
            float zz = fminf(fmaxf(av[j], -30.f), 30.f);
            float s = 1.f / (1.f + __expf(-zz));
            aL[m * ALS + c0 + j] = to_h(s);
        }
    }
    __syncthreads();

    // ---- phase 2: long GEMM  y1 = relu((a .* window) @ w1 + b1), M=64 K=2048 N=256 ----
    {
        f4 acc[4][4];
#pragma unroll
        for (int mt = 0; mt < 4; mt++)
#pragma unroll
            for (int i = 0; i < 4; i++)
#pragma unroll
                for (int r = 0; r < 4; r++) acc[mt][i][r] = 0.f;
        const h8* w1v = (const h8*)w1p;
        for (int kk = 0; kk < 64; kk++) {
            const int wf = kk >> 1;
            const int c0 = ((kk & 1) << 5) + quad * 8;
            h8 bc[4];
#pragma unroll
            for (int i = 0; i < 4; i++) bc[i] = w1v[(kk * 16 + wv * 4 + i) * 64 + lane];
            h8 af[4];
#pragma unroll
            for (int mt = 0; mt < 4; mt++) {
                int m = mt * 16 + rl;
                h8 xv = *(const h8*)(xcL + (m + wf) * XCS + c0);
                h8 av = *(const h8*)(aL + m * ALS + c0);
                af[mt] = xv * av;
            }
#pragma unroll
            for (int mt = 0; mt < 4; mt++)
#pragma unroll
                for (int i = 0; i < 4; i++)
                    acc[mt][i] = __builtin_amdgcn_mfma_f32_16x16x32_f16(af[mt], bc[i], acc[mt][i], 0, 0, 0);
        }
#pragma unroll
        for (int i = 0; i < 4; i++) {
            int n = wv * 64 + i * 16 + rl;
            float bb = b1[n];
#pragma unroll
            for (int mt = 0; mt < 4; mt++)
#pragma unroll
                for (int r = 0; r < 4; r++) {
                    int m = mt * 16 + quad * 4 + r;
                    y1L[m * Y1S + n] = to_h(fmaxf(acc[mt][i][r] + bb, 0.f));
                }
        }
    }
    __syncthreads();

    // ---- phase 3: h2 = relu(y1 @ w2 + b2) (M=64 K=256 N=128), kept in regs ----
    f4 acc2[4][2];
#pragma unroll
    for (int mt = 0; mt < 4; mt++)
#pragma unroll
        for (int j = 0; j < 2; j++)
#pragma unroll
            for (int r = 0; r < 4; r++) acc2[mt][j][r] = 0.f;
    {
        const h8* w2v = (const h8*)w2p;
        for (int kk = 0; kk < 8; kk++) {
            h8 bc0 = w2v[(kk * 8 + wv * 2 + 0) * 64 + lane];
            h8 bc1 = w2v[(kk * 8 + wv * 2 + 1) * 64 + lane];
#pragma unroll
            for (int mt = 0; mt < 4; mt++) {
                h8 av = *(const h8*)(y1L + (mt * 16 + rl) * Y1S + kk * 32 + quad * 8);
                acc2[mt][0] = __builtin_amdgcn_mfma_f32_16x16x32_f16(av, bc0, acc2[mt][0], 0, 0, 0);
                acc2[mt][1] = __builtin_amdgcn_mfma_f32_16x16x32_f16(av, bc1, acc2[mt][1], 0, 0, 0);
            }
        }
    }

    // ---- phase 4: h_short = relu((a .* window[-8:]) @ sw + sb) (K=512 N=128) ----
    f4 accS[4][2];
#pragma unroll
    for (int mt = 0; mt < 4; mt++)
#pragma unroll
        for (int j = 0; j < 2; j++)
#pragma unroll
            for (int r = 0; r < 4; r++) accS[mt][j][r] = 0.f;
    {
        const h8* swv = (const h8*)swp;
        for (int kk = 0; kk < 16; kk++) {
            h8 bc0 = swv[(kk * 8 + wv * 2 + 0) * 64 + lane];
            h8 bc1 = swv[(kk * 8 + wv * 2 + 1) * 64 + lane];
            const int wf = 24 + (kk >> 1);
            const int c0 = ((kk & 1) << 5) + quad * 8;
#pragma unroll
            for (int mt = 0; mt < 4; mt++) {
                int m = mt * 16 + rl;
                h8 xv = *(const h8*)(xcL + (m + wf) * XCS + c0);
                h8 av2 = *(const h8*)(aL + m * ALS + c0);
                h8 af = xv * av2;
                accS[mt][0] = __builtin_amdgcn_mfma_f32_16x16x32_f16(af, bc0, accS[mt][0], 0, 0, 0);
                accS[mt][1] = __builtin_amdgcn_mfma_f32_16x16x32_f16(af, bc1, accS[mt][1], 0, 0, 0);
            }
        }
    }
    __syncthreads();  // all phase-3 reads of y1L done before hL overwrite

    // ---- phase 5a: hL[m][0:128]=relu(h2), hL[m][128:256]=relu(h_short) (fp16, over y1L) ----
    {
#pragma unroll
        for (int j = 0; j < 2; j++) {
            int n = wv * 32 + j * 16 + rl;
            float bb2 = b2[n], bbs = sb[n];
#pragma unroll
            for (int mt = 0; mt < 4; mt++)
#pragma unroll
                for (int r = 0; r < 4; r++) {
                    int m = mt * 16 + quad * 4 + r;
                    y1L[m * Y1S + n]       = to_h(fmaxf(acc2[mt][j][r] + bb2, 0.f));
                    y1L[m * Y1S + 128 + n] = to_h(fmaxf(accS[mt][j][r] + bbs, 0.f));
                }
        }
    }
    __syncthreads();

    // ---- phase 5b: out = sigmoid(h @ wo + bo), 128 threads, direct dot ----
    if (tid < 128) {
        int m = tid & 63, o = tid >> 6;
        float z = bo[o];
        const half_t* hrow = y1L + m * Y1S;
        for (int nb = 0; nb < 32; nb++) {
            h8 hv = *(const h8*)(hrow + nb * 8);
#pragma unroll
            for (int j = 0; j < 8; j++)
                z += (float)hv[j] * woL[(nb * 8 + j) * 2 + o];
        }
        z = fminf(fmaxf(z, -30.f), 30.f);
        float sg = 1.f / (1.f + __expf(-z));
        out[((size_t)(b * 4096 + t0 + m)) * 2 + o] = sg;
    }
}

extern "C" void kernel_launch(void* const* d_in, const int* in_sizes, int n_in,
                              void* d_out, int out_size, void* d_ws, size_t ws_size,
                              hipStream_t stream) {
    const float* x      = (const float*)d_in[0];
    const float* conv_w = (const float*)d_in[1];
    const float* conv_b = (const float*)d_in[2];
    const float* se_w1  = (const float*)d_in[3];
    const float* se_b1  = (const float*)d_in[4];
    const float* se_w2  = (const float*)d_in[5];
    const float* se_b2  = (const float*)d_in[6];
    const float* w1     = (const float*)d_in[7];
    const float* b1     = (const float*)d_in[8];
    const float* w2     = (const float*)d_in[9];
    const float* b2     = (const float*)d_in[10];
    const float* sw     = (const float*)d_in[11];
    const float* sb     = (const float*)d_in[12];
    const float* wo     = (const float*)d_in[13];
    const float* bo     = (const float*)d_in[14];
    half_t* wsH = (half_t*)d_ws;

    hipLaunchKernelGGL(pack_k, dim3(2465), dim3(256), 0, stream, w1, w2, sw, conv_w, wsH);
    hipLaunchKernelGGL(beat_main, dim3(512), dim3(256), 0, stream,
                       x, conv_b, se_w1, se_b1, se_w2, se_b2, b1, b2, sb, wo, bo,
                       wsH, wsH + 524288, wsH + 557056, wsH + 622592,
                       (float*)d_out);
}

// Round 4
// 179.855 us; speedup vs baseline: 1.1505x; 1.1505x over previous
//
#include <hip/hip_runtime.h>

typedef _Float16 half_t;
typedef __attribute__((ext_vector_type(8))) _Float16 h8;
typedef __attribute__((ext_vector_type(2))) _Float16 h2v;
typedef __attribute__((ext_vector_type(4))) float f4;
typedef __attribute__((ext_vector_type(2))) float f2v;

// fp32 -> fp16 with inf/NaN killing (fmaxf/fminf return the non-NaN operand).
__device__ __forceinline__ half_t to_h(float v) {
    v = fminf(fmaxf(v, -60000.f), 60000.f);
    return (half_t)v;
}

// ---------------- pack kernel (source-coalesced): fp32 weights -> fp16 MFMA-B frags ----
// ws layout (half elements):
//   w1p: [0, 524288)          [kk=64][nt=16][lane=64][j=8]
//   w2p: [524288, 557056)     [kk=8][nt=8][64][8]
//   swp: [557056, 622592)     [kk=16][nt=8][64][8]
//   cwp: [622592, 630912)     [p=k*13+ip][c=64][r=2]
__global__ void pack_k(const float* __restrict__ w1, const float* __restrict__ w2,
                       const float* __restrict__ sw, const float* __restrict__ cw,
                       half_t* __restrict__ wsH) {
    int i = blockIdx.x * 256 + threadIdx.x;
    if (i < 524288) {                       // w1 [2048][256], i = k*256+n
        int k = i >> 8, n = i & 255;
        int kk = k >> 5, rem = k & 31, Lh = rem >> 3, j = rem & 7;
        int nt = n >> 4, L = Lh * 16 + (n & 15);
        wsH[((kk * 16 + nt) * 64 + L) * 8 + j] = to_h(w1[i]);
    } else if (i < 557056) {                // w2 [256][128]
        int o = i - 524288; int k = o >> 7, n = o & 127;
        int kk = k >> 5, rem = k & 31, Lh = rem >> 3, j = rem & 7;
        int nt = n >> 4, L = Lh * 16 + (n & 15);
        wsH[524288 + ((kk * 8 + nt) * 64 + L) * 8 + j] = to_h(w2[o]);
    } else if (i < 622592) {                // sw [512][128]
        int o = i - 557056; int k = o >> 7, n = o & 127;
        int kk = k >> 5, rem = k & 31, Lh = rem >> 3, j = rem & 7;
        int nt = n >> 4, L = Lh * 16 + (n & 15);
        wsH[557056 + ((kk * 8 + nt) * 64 + L) * 8 + j] = to_h(sw[o]);
    } else if (i < 630912) {                // cw [5][26][64], i-base = (k*26+ci)*64+c
        int o = i - 622592; int c = o & 63, rest = o >> 6;
        int k = rest / 26, ci = rest - k * 26;
        int ip = ci >> 1, r = ci & 1;
        wsH[622592 + ((k * 13 + ip) * 64 + c) * 2 + r] = to_h(cw[o]);
    }
}

// ---------------- main fused kernel ----------------
// block = 256 thr (4 waves), one b and 32 consecutive t. Grid = 8*128 = 1024.
#define XCS 72   // xcL row stride (halfs), 63 rows, frame f <-> t = t0-31+f
#define ALS 72   // aL row stride (halfs), 32 rows
#define Y1S 264  // y1L / hL row stride (halfs), 32 rows
#define SLS 68   // sLf row stride (floats)
#define HLS 20   // hidL row stride (floats)

__global__ __launch_bounds__(256) void beat_main(
    const float* __restrict__ x,
    const float* __restrict__ conv_b,
    const float* __restrict__ se_w1, const float* __restrict__ se_b1,
    const float* __restrict__ se_w2, const float* __restrict__ se_b2,
    const float* __restrict__ b1, const float* __restrict__ b2,
    const float* __restrict__ sb,
    const float* __restrict__ wo, const float* __restrict__ bo,
    const half_t* __restrict__ w1p, const half_t* __restrict__ w2p,
    const half_t* __restrict__ swp, const half_t* __restrict__ cwp,
    float* __restrict__ out) {

    __shared__ __align__(16) char smem[32640];
    half_t* xcL = (half_t*)smem;             // 63*72*2 = 9072 (pad->9088)
    half_t* aL  = (half_t*)(smem + 9088);    // 32*72*2 = 4608 -> 13696
    char*   U   = smem + 13696;              // 16896-byte phase union
    half_t* xLh = (half_t*)U;                // phase0: 67 rows * 28 halfs = 3752
    float*  sLf = (float*)U;                 // phase1: 32*68 floats = 8704
    float*  hidL= (float*)(U + 8704);        // phase1: 32*20 floats = 2560
    half_t* y1L = (half_t*)U;                // phase2+: 32*264 halfs = 16896
    float*  woL = (float*)(smem + 30592);    // 512 floats -> 32640

    const int tid = threadIdx.x;
    const int bi = blockIdx.x;
    const int b = bi >> 7;
    const int t0 = (bi & 127) << 5;
    const int lane = tid & 63, wv = tid >> 6;
    const int quad = lane >> 4, rl = lane & 15;

    // ---- phase 0a: stage x (fp16 pairs) + wo ----
    ((f2v*)woL)[tid] = ((const f2v*)wo)[tid];       // 512 floats
    for (int idx = tid; idx < 67 * 13; idx += 256) {
        int fi = idx / 13, ip = idx - fi * 13;
        int tx = t0 - 35 + fi;
        h2v v;
        if (tx >= 0) {
            const float* xp = x + ((size_t)(b * 4096 + tx)) * 26 + 2 * ip;
            v[0] = to_h(xp[0]); v[1] = to_h(xp[1]);
        } else { v[0] = (_Float16)0.f; v[1] = (_Float16)0.f; }
        *(h2v*)(xLh + fi * 28 + 2 * ip) = v;
    }
    __syncthreads();

    // ---- phase 0b: causal conv (K=5, 26->64) + relu -> xcL (fp16), 63 rows ----
    {
        int c = tid & 63, f0 = tid >> 6;
        h2v cwr[65];
        const h2v* cwg = (const h2v*)cwp;           // global, coalesced b32 per lane
#pragma unroll
        for (int p = 0; p < 65; p++) cwr[p] = cwg[p * 64 + c];
        float bias = conv_b[c];
        for (int f = f0; f < 63; f += 4) {
            int t = t0 - 31 + f;
            float r0 = 0.f;
            if (t >= 0) {
                h2v accp; accp[0] = (_Float16)0.f; accp[1] = (_Float16)0.f;
#pragma unroll
                for (int k = 0; k < 5; k++)
#pragma unroll
                    for (int ip = 0; ip < 13; ip++) {
                        h2v xp = *(const h2v*)(xLh + (f + k) * 28 + 2 * ip);
                        accp += xp * cwr[k * 13 + ip];
                    }
                r0 = fmaxf((float)accp[0] + (float)accp[1] + bias, 0.f);
            }
            xcL[f * XCS + c] = to_h(r0);
        }
    }
    __syncthreads();

    // ---- phase 1a: sliding window means s[m][c], m in [0,32) ----
    {
        int c = tid & 63, mb = tid >> 6;
        float run = 0.f;
#pragma unroll 8
        for (int w = 0; w < 32; w++) run += (float)xcL[(mb + w) * XCS + c];
        sLf[mb * SLS + c] = run * (1.f / 32.f);
        for (int m = mb + 4; m < 32; m += 4) {
#pragma unroll
            for (int d = 0; d < 4; d++) {
                run += (float)xcL[(m + 28 + d) * XCS + c];
                run -= (float)xcL[(m - 4 + d) * XCS + c];
            }
            sLf[m * SLS + c] = run * (1.f / 32.f);
        }
    }
    __syncthreads();

    // ---- phase 1b: SE hidden = relu(s @ se_w1 + se_b1), 32 m x 16 h ----
    {
        int m = tid >> 3, hh = (tid & 7) * 2;
        float acc0 = se_b1[hh], acc1 = se_b1[hh + 1];
        for (int c = 0; c < 64; c++) {
            float sv = sLf[m * SLS + c];
            f2v wq = *(const f2v*)(se_w1 + c * 16 + hh);
            acc0 += sv * wq[0]; acc1 += sv * wq[1];
        }
        hidL[m * HLS + hh] = fmaxf(acc0, 0.f);
        hidL[m * HLS + hh + 1] = fmaxf(acc1, 0.f);
    }
    __syncthreads();

    // ---- phase 1c: a = sigmoid(hidden @ se_w2 + se_b2) -> aL (fp16) ----
    {
        int m = tid >> 3, c0 = (tid & 7) * 8;
        float av[8];
#pragma unroll
        for (int j = 0; j < 8; j++) av[j] = se_b2[c0 + j];
        for (int h = 0; h < 16; h++) {
            float hv = hidL[m * HLS + h];
            const f4* wv4 = (const f4*)(se_w2 + h * 64 + c0);
            f4 wq0 = wv4[0], wq1 = wv4[1];
#pragma unroll
            for (int j = 0; j < 4; j++) { av[j] += hv * wq0[j]; av[4 + j] += hv * wq1[j]; }
        }
#pragma unroll
        for (int j = 0; j < 8; j++) {
            float zz = fminf(fmaxf(av[j], -30.f), 30.f);
            float s = 1.f / (1.f + __expf(-zz));
            aL[m * ALS + c0 + j] = to_h(s);
        }
    }
    __syncthreads();

    // ---- phase 2: y1 = relu((a .* window) @ w1 + b1), M=32 K=2048 N=256 ----
    {
        f4 acc[2][4];
#pragma unroll
        for (int mt = 0; mt < 2; mt++)
#pragma unroll
            for (int i = 0; i < 4; i++)
#pragma unroll
                for (int r = 0; r < 4; r++) acc[mt][i][r] = 0.f;
        const h8* w1v = (const h8*)w1p;
        h8 bcA[4], bcB[4];
#pragma unroll
        for (int i = 0; i < 4; i++) bcA[i] = w1v[(wv * 4 + i) * 64 + lane];
        for (int kk = 0; kk < 64; kk += 2) {
            const int wf = kk >> 1;
            // prefetch odd half
#pragma unroll
            for (int i = 0; i < 4; i++) bcB[i] = w1v[((kk + 1) * 16 + wv * 4 + i) * 64 + lane];
            {   // even half: c0 = quad*8
                const int c0 = quad * 8;
                h8 af[2];
#pragma unroll
                for (int mt = 0; mt < 2; mt++) {
                    int m = mt * 16 + rl;
                    h8 xv = *(const h8*)(xcL + (m + wf) * XCS + c0);
                    h8 av = *(const h8*)(aL + m * ALS + c0);
                    af[mt] = xv * av;
                }
#pragma unroll
                for (int mt = 0; mt < 2; mt++)
#pragma unroll
                    for (int i = 0; i < 4; i++)
                        acc[mt][i] = __builtin_amdgcn_mfma_f32_16x16x32_f16(af[mt], bcA[i], acc[mt][i], 0, 0, 0);
            }
            // prefetch next even half (wraps harmlessly on last iter)
#pragma unroll
            for (int i = 0; i < 4; i++) bcA[i] = w1v[(((kk + 2) & 63) * 16 + wv * 4 + i) * 64 + lane];
            {   // odd half: c0 = 32 + quad*8
                const int c0 = 32 + quad * 8;
                h8 af[2];
#pragma unroll
                for (int mt = 0; mt < 2; mt++) {
                    int m = mt * 16 + rl;
                    h8 xv = *(const h8*)(xcL + (m + wf) * XCS + c0);
                    h8 av = *(const h8*)(aL + m * ALS + c0);
                    af[mt] = xv * av;
                }
#pragma unroll
                for (int mt = 0; mt < 2; mt++)
#pragma unroll
                    for (int i = 0; i < 4; i++)
                        acc[mt][i] = __builtin_amdgcn_mfma_f32_16x16x32_f16(af[mt], bcB[i], acc[mt][i], 0, 0, 0);
            }
        }
#pragma unroll
        for (int i = 0; i < 4; i++) {
            int n = wv * 64 + i * 16 + rl;
            float bb = b1[n];
#pragma unroll
            for (int mt = 0; mt < 2; mt++)
#pragma unroll
                for (int r = 0; r < 4; r++) {
                    int m = mt * 16 + quad * 4 + r;
                    y1L[m * Y1S + n] = to_h(fmaxf(acc[mt][i][r] + bb, 0.f));
                }
        }
    }
    __syncthreads();

    // ---- phase 3: h2 = relu(y1 @ w2 + b2) (M=32 K=256 N=128), kept in regs ----
    f4 acc2[2][2];
#pragma unroll
    for (int mt = 0; mt < 2; mt++)
#pragma unroll
        for (int j = 0; j < 2; j++)
#pragma unroll
            for (int r = 0; r < 4; r++) acc2[mt][j][r] = 0.f;
    {
        const h8* w2v = (const h8*)w2p;
        h8 bA0 = w2v[(wv * 2 + 0) * 64 + lane];
        h8 bA1 = w2v[(wv * 2 + 1) * 64 + lane];
        for (int kk = 0; kk < 8; kk += 2) {
            h8 bB0 = w2v[((kk + 1) * 8 + wv * 2 + 0) * 64 + lane];
            h8 bB1 = w2v[((kk + 1) * 8 + wv * 2 + 1) * 64 + lane];
#pragma unroll
            for (int mt = 0; mt < 2; mt++) {
                h8 av = *(const h8*)(y1L + (mt * 16 + rl) * Y1S + kk * 32 + quad * 8);
                acc2[mt][0] = __builtin_amdgcn_mfma_f32_16x16x32_f16(av, bA0, acc2[mt][0], 0, 0, 0);
                acc2[mt][1] = __builtin_amdgcn_mfma_f32_16x16x32_f16(av, bA1, acc2[mt][1], 0, 0, 0);
            }
            bA0 = w2v[((((kk + 2) & 7)) * 8 + wv * 2 + 0) * 64 + lane];
            bA1 = w2v[((((kk + 2) & 7)) * 8 + wv * 2 + 1) * 64 + lane];
#pragma unroll
            for (int mt = 0; mt < 2; mt++) {
                h8 av = *(const h8*)(y1L + (mt * 16 + rl) * Y1S + (kk + 1) * 32 + quad * 8);
                acc2[mt][0] = __builtin_amdgcn_mfma_f32_16x16x32_f16(av, bB0, acc2[mt][0], 0, 0, 0);
                acc2[mt][1] = __builtin_amdgcn_mfma_f32_16x16x32_f16(av, bB1, acc2[mt][1], 0, 0, 0);
            }
        }
    }

    // ---- phase 4: h_short = relu((a .* window[-8:]) @ sw + sb) (K=512 N=128) ----
    f4 accS[2][2];
#pragma unroll
    for (int mt = 0; mt < 2; mt++)
#pragma unroll
        for (int j = 0; j < 2; j++)
#pragma unroll
            for (int r = 0; r < 4; r++) accS[mt][j][r] = 0.f;
    {
        const h8* swv = (const h8*)swp;
        h8 bA0 = swv[(wv * 2 + 0) * 64 + lane];
        h8 bA1 = swv[(wv * 2 + 1) * 64 + lane];
        for (int kk = 0; kk < 16; kk += 2) {
            const int wf = 24 + (kk >> 1);
            h8 bB0 = swv[((kk + 1) * 8 + wv * 2 + 0) * 64 + lane];
            h8 bB1 = swv[((kk + 1) * 8 + wv * 2 + 1) * 64 + lane];
            {
                const int c0 = quad * 8;
#pragma unroll
                for (int mt = 0; mt < 2; mt++) {
                    int m = mt * 16 + rl;
                    h8 xv = *(const h8*)(xcL + (m + wf) * XCS + c0);
                    h8 av2 = *(const h8*)(aL + m * ALS + c0);
                    h8 af = xv * av2;
                    accS[mt][0] = __builtin_amdgcn_mfma_f32_16x16x32_f16(af, bA0, accS[mt][0], 0, 0, 0);
                    accS[mt][1] = __builtin_amdgcn_mfma_f32_16x16x32_f16(af, bA1, accS[mt][1], 0, 0, 0);
                }
            }
            bA0 = swv[((((kk + 2) & 15)) * 8 + wv * 2 + 0) * 64 + lane];
            bA1 = swv[((((kk + 2) & 15)) * 8 + wv * 2 + 1) * 64 + lane];
            {
                const int c0 = 32 + quad * 8;
#pragma unroll
                for (int mt = 0; mt < 2; mt++) {
                    int m = mt * 16 + rl;
                    h8 xv = *(const h8*)(xcL + (m + wf) * XCS + c0);
                    h8 av2 = *(const h8*)(aL + m * ALS + c0);
                    h8 af = xv * av2;
                    accS[mt][0] = __builtin_amdgcn_mfma_f32_16x16x32_f16(af, bB0, accS[mt][0], 0, 0, 0);
                    accS[mt][1] = __builtin_amdgcn_mfma_f32_16x16x32_f16(af, bB1, accS[mt][1], 0, 0, 0);
                }
            }
        }
    }
    __syncthreads();  // phase-3 reads of y1L done before overwrite

    // ---- phase 5a: hL[m][0:128]=relu(h2), hL[m][128:256]=relu(h_short) ----
    {
#pragma unroll
        for (int j = 0; j < 2; j++) {
            int n = wv * 32 + j * 16 + rl;
            float bb2 = b2[n], bbs = sb[n];
#pragma unroll
            for (int mt = 0; mt < 2; mt++)
#pragma unroll
                for (int r = 0; r < 4; r++) {
                    int m = mt * 16 + quad * 4 + r;
                    y1L[m * Y1S + n]       = to_h(fmaxf(acc2[mt][j][r] + bb2, 0.f));
                    y1L[m * Y1S + 128 + n] = to_h(fmaxf(accS[mt][j][r] + bbs, 0.f));
                }
        }
    }
    __syncthreads();

    // ---- phase 5b: out = sigmoid(h @ wo + bo), 64 threads, direct dot ----
    if (tid < 64) {
        int m = tid >> 1, o = tid & 1;
        float z = bo[o];
        const half_t* hrow = y1L + m * Y1S;
        for (int nb = 0; nb < 32; nb++) {
            h8 hv = *(const h8*)(hrow + nb * 8);
#pragma unroll
            for (int j = 0; j < 8; j++)
                z += (float)hv[j] * woL[(nb * 8 + j) * 2 + o];
        }
        z = fminf(fmaxf(z, -30.f), 30.f);
        float sg = 1.f / (1.f + __expf(-z));
        out[((size_t)(b * 4096 + t0 + m)) * 2 + o] = sg;
    }
}

extern "C" void kernel_launch(void* const* d_in, const int* in_sizes, int n_in,
                              void* d_out, int out_size, void* d_ws, size_t ws_size,
                              hipStream_t stream) {
    const float* x      = (const float*)d_in[0];
    const float* conv_w = (const float*)d_in[1];
    const float* conv_b = (const float*)d_in[2];
    const float* se_w1  = (const float*)d_in[3];
    const float* se_b1  = (const float*)d_in[4];
    const float* se_w2  = (const float*)d_in[5];
    const float* se_b2  = (const float*)d_in[6];
    const float* w1     = (const float*)d_in[7];
    const float* b1     = (const float*)d_in[8];
    const float* w2     = (const float*)d_in[9];
    const float* b2     = (const float*)d_in[10];
    const float* sw     = (const float*)d_in[11];
    const float* sb     = (const float*)d_in[12];
    const float* wo     = (const float*)d_in[13];
    const float* bo     = (const float*)d_in[14];
    half_t* wsH = (half_t*)d_ws;

    hipLaunchKernelGGL(pack_k, dim3(2465), dim3(256), 0, stream, w1, w2, sw, conv_w, wsH);
    hipLaunchKernelGGL(beat_main, dim3(1024), dim3(256), 0, stream,
                       x, conv_b, se_w1, se_b1, se_w2, se_b2, b1, b2, sb, wo, bo,
                       wsH, wsH + 524288, wsH + 557056, wsH + 622592,
                       (float*)d_out);
}

// Round 5
// 152.697 us; speedup vs baseline: 1.3551x; 1.1779x over previous
//
#include <hip/hip_runtime.h>

typedef _Float16 half_t;
typedef __attribute__((ext_vector_type(8))) _Float16 h8;
typedef __attribute__((ext_vector_type(2))) _Float16 h2v;
typedef __attribute__((ext_vector_type(4))) float f4;
typedef __attribute__((ext_vector_type(2))) float f2v;

// fp32 -> fp16 with inf/NaN killing (fmaxf/fminf return the non-NaN operand).
__device__ __forceinline__ half_t to_h(float v) {
    v = fminf(fmaxf(v, -60000.f), 60000.f);
    return (half_t)v;
}

// ---------------- pack kernel: bilaterally-coalesced fp32 -> fp16 MFMA-B frags ----------
// ws layout (half elements):
//   w1p: [0, 524288)          [kk=64][nt=16][lane=64][j=8]
//   w2p: [524288, 557056)     [kk=8][nt=8][64][8]
//   swp: [557056, 622592)     [kk=16][nt=8][64][8]
//   cwp: [622592, 630912)     [p=k*13+ip][c=64][r=2]
// Jobs: one h8 fragment per thread (16B coalesced store); reads are 64B-chunk coalesced.
__global__ void pack_k(const float* __restrict__ w1, const float* __restrict__ w2,
                       const float* __restrict__ sw, const float* __restrict__ cw,
                       half_t* __restrict__ wsH) {
    int i = blockIdx.x * 256 + threadIdx.x;
    if (i < 65536) {                        // w1 [2048][256]: 65536 h8 jobs
        int L = i & 63, nt = (i >> 6) & 15, kk = i >> 10;
        int k0 = kk * 32 + ((L >> 4) << 3), n = (nt << 4) + (L & 15);
        h8 v;
#pragma unroll
        for (int j = 0; j < 8; j++) v[j] = to_h(w1[(k0 + j) * 256 + n]);
        *(h8*)(wsH + ((((kk * 16 + nt) * 64 + L)) << 3)) = v;
    } else if (i < 69632) {                 // w2 [256][128]: 4096 jobs
        int o = i - 65536;
        int L = o & 63, nt = (o >> 6) & 7, kk = o >> 9;
        int k0 = kk * 32 + ((L >> 4) << 3), n = (nt << 4) + (L & 15);
        h8 v;
#pragma unroll
        for (int j = 0; j < 8; j++) v[j] = to_h(w2[(k0 + j) * 128 + n]);
        *(h8*)(wsH + 524288 + ((((kk * 8 + nt) * 64 + L)) << 3)) = v;
    } else if (i < 77824) {                 // sw [512][128]: 8192 jobs
        int o = i - 69632;
        int L = o & 63, nt = (o >> 6) & 7, kk = o >> 9;
        int k0 = kk * 32 + ((L >> 4) << 3), n = (nt << 4) + (L & 15);
        h8 v;
#pragma unroll
        for (int j = 0; j < 8; j++) v[j] = to_h(sw[(k0 + j) * 128 + n]);
        *(h8*)(wsH + 557056 + ((((kk * 8 + nt) * 64 + L)) << 3)) = v;
    } else if (i < 86144) {                 // cw [5][26][64]: 8320 element jobs
        int o = i - 77824;
        int c = o & 63, rest = o >> 6;
        int k = rest / 26, ci = rest - k * 26;
        int ip = ci >> 1, r = ci & 1;
        wsH[622592 + ((k * 13 + ip) * 64 + c) * 2 + r] = to_h(cw[o]);
    }
}

// ---------------- main fused kernel ----------------
// block = 512 thr (8 waves), one b and 64 consecutive t. Grid = 8*64 = 512 (2 blocks/CU).
#define XCS 72   // xcL row stride (halfs), 95 rows, frame f <-> t = t0-31+f
#define ALS 72   // aL row stride (halfs), 64 rows
#define Y1S 264  // y1L / hL row stride (halfs), 64 rows
#define SLS 68   // sLf row stride (floats)
#define HLS 20   // hidL row stride (floats)

#define MFMA16(a, b, c) __builtin_amdgcn_mfma_f32_16x16x32_f16(a, b, c, 0, 0, 0)

__global__ __launch_bounds__(512, 4) void beat_main(
    const float* __restrict__ x,
    const float* __restrict__ conv_b,
    const float* __restrict__ se_w1, const float* __restrict__ se_b1,
    const float* __restrict__ se_w2, const float* __restrict__ se_b2,
    const float* __restrict__ b1, const float* __restrict__ b2,
    const float* __restrict__ sb,
    const float* __restrict__ wo, const float* __restrict__ bo,
    const half_t* __restrict__ w1p, const half_t* __restrict__ w2p,
    const half_t* __restrict__ swp, const half_t* __restrict__ cwp,
    float* __restrict__ out) {

    __shared__ __align__(16) char smem[58752];
    half_t* xcL = (half_t*)smem;             // 95*72*2 = 13680 -> pad 13696
    half_t* aL  = (half_t*)(smem + 13696);   // 64*72*2 = 9216 -> 22912
    char*   U   = smem + 22912;              // 33792-byte phase union
    half_t* xLh = (half_t*)U;                // phase0: 99*28 halfs = 5544
    float*  sLf = (float*)U;                 // phase1: 64*68 floats = 17408
    float*  hidL= (float*)(U + 17408);       // phase1: 64*20 floats = 5120
    half_t* y1L = (half_t*)U;                // phase2+: 64*264 halfs = 33792
    float*  woL = (float*)(smem + 56704);    // 512 floats -> 58752

    const int tid = threadIdx.x;
    const int bi = blockIdx.x;
    const int b = bi >> 6;
    const int t0 = (bi & 63) << 6;
    const int lane = tid & 63, wv = tid >> 6;     // wv in 0..7
    const int quad = lane >> 4, rl = lane & 15;
    const int mg = wv >> 2;                        // m-group: rows mg*32..+32
    const int ng = wv & 3;                         // n-group (phase 2): cols ng*64..+64
    const int nq = wv & 3;                         // n-group (phase 3/4): cols nq*32..+32

    // ---- phase 0a: stage x (fp16 pairs) + wo ----
    if (tid < 256) ((f2v*)woL)[tid] = ((const f2v*)wo)[tid];   // 512 floats
    for (int idx = tid; idx < 99 * 13; idx += 512) {
        int fi = idx / 13, ip = idx - fi * 13;
        int tx = t0 - 35 + fi;
        h2v v;
        if (tx >= 0) {
            const float* xp = x + ((size_t)(b * 4096 + tx)) * 26 + 2 * ip;
            v[0] = to_h(xp[0]); v[1] = to_h(xp[1]);
        } else { v[0] = (_Float16)0.f; v[1] = (_Float16)0.f; }
        *(h2v*)(xLh + fi * 28 + 2 * ip) = v;
    }
    __syncthreads();

    // ---- phase 0b: causal conv (K=5, 26->64) + relu -> xcL (fp16), 95 rows ----
    {
        int c = tid & 63, f0 = tid >> 6;          // f0 in 0..7
        h2v cwr[65];
        const h2v* cwg = (const h2v*)cwp;         // coalesced b32 per lane
#pragma unroll
        for (int p = 0; p < 65; p++) cwr[p] = cwg[p * 64 + c];
        float bias = conv_b[c];
        for (int f = f0; f < 95; f += 8) {
            int t = t0 - 31 + f;
            float r0 = 0.f;
            if (t >= 0) {
                h2v accp; accp[0] = (_Float16)0.f; accp[1] = (_Float16)0.f;
#pragma unroll
                for (int k = 0; k < 5; k++)
#pragma unroll
                    for (int ip = 0; ip < 13; ip++) {
                        h2v xp = *(const h2v*)(xLh + (f + k) * 28 + 2 * ip);
                        accp += xp * cwr[k * 13 + ip];
                    }
                r0 = fmaxf((float)accp[0] + (float)accp[1] + bias, 0.f);
            }
            xcL[f * XCS + c] = to_h(r0);
        }
    }
    __syncthreads();

    // ---- phase 1a: sliding window means s[m][c], m in [0,64), 8 m-lanes/thread ----
    {
        int c = tid & 63, mb = tid >> 6;          // mb in 0..7
        float run = 0.f;
#pragma unroll 8
        for (int w = 0; w < 32; w++) run += (float)xcL[(mb + w) * XCS + c];
        sLf[mb * SLS + c] = run * (1.f / 32.f);
        for (int m = mb + 8; m < 64; m += 8) {
#pragma unroll
            for (int d = 0; d < 8; d++) {
                run += (float)xcL[(m + 24 + d) * XCS + c];
                run -= (float)xcL[(m - 8 + d) * XCS + c];
            }
            sLf[m * SLS + c] = run * (1.f / 32.f);
        }
    }
    __syncthreads();

    // ---- phase 1b: SE hidden = relu(s @ se_w1 + se_b1), 64 m x 16 h ----
    {
        int m = tid >> 3, hh = (tid & 7) * 2;
        float acc0 = se_b1[hh], acc1 = se_b1[hh + 1];
        for (int c = 0; c < 64; c++) {
            float sv = sLf[m * SLS + c];
            f2v wq = *(const f2v*)(se_w1 + c * 16 + hh);
            acc0 += sv * wq[0]; acc1 += sv * wq[1];
        }
        hidL[m * HLS + hh] = fmaxf(acc0, 0.f);
        hidL[m * HLS + hh + 1] = fmaxf(acc1, 0.f);
    }
    __syncthreads();

    // ---- phase 1c: a = sigmoid(hidden @ se_w2 + se_b2) -> aL (fp16) ----
    {
        int m = tid >> 3, c0 = (tid & 7) * 8;
        float av[8];
#pragma unroll
        for (int j = 0; j < 8; j++) av[j] = se_b2[c0 + j];
        for (int h = 0; h < 16; h++) {
            float hv = hidL[m * HLS + h];
            const f4* wv4 = (const f4*)(se_w2 + h * 64 + c0);
            f4 wq0 = wv4[0], wq1 = wv4[1];
#pragma unroll
            for (int j = 0; j < 4; j++) { av[j] += hv * wq0[j]; av[4 + j] += hv * wq1[j]; }
        }
#pragma unroll
        for (int j = 0; j < 8; j++) {
            float zz = fminf(fmaxf(av[j], -30.f), 30.f);
            float s = 1.f / (1.f + __expf(-zz));
            aL[m * ALS + c0 + j] = to_h(s);
        }
    }
    __syncthreads();

    // ---- phase 2: y1 = relu((a .* window) @ w1 + b1), M=64 K=2048 N=256 ----
    // wave (mg,ng): rows mg*32+mt*16, cols ng*64+i*16. Prefetch distance = 2 kk-steps.
    {
        f4 acc[2][4];
#pragma unroll
        for (int mt = 0; mt < 2; mt++)
#pragma unroll
            for (int i = 0; i < 4; i++)
#pragma unroll
                for (int r = 0; r < 4; r++) acc[mt][i][r] = 0.f;
        const h8* w1v = (const h8*)w1p;
        const int fb = ng * 4;
        h8 bA[4], bB[4], bC[4], bD[4];
#pragma unroll
        for (int i = 0; i < 4; i++) bA[i] = w1v[(fb + i) * 64 + lane];
#pragma unroll
        for (int i = 0; i < 4; i++) bB[i] = w1v[(16 + fb + i) * 64 + lane];
#pragma unroll 2
        for (int kk = 0; kk < 64; kk += 2) {
            const int k2 = (kk + 2) & 63, k3 = (kk + 3) & 63;  // wrap harmless on last iter
#pragma unroll
            for (int i = 0; i < 4; i++) bC[i] = w1v[(k2 * 16 + fb + i) * 64 + lane];
#pragma unroll
            for (int i = 0; i < 4; i++) bD[i] = w1v[(k3 * 16 + fb + i) * 64 + lane];
            const int wf = kk >> 1;
            {   // even kk: c0 = quad*8
                const int c0 = quad * 8;
#pragma unroll
                for (int mt = 0; mt < 2; mt++) {
                    int m = mg * 32 + mt * 16 + rl;
                    h8 xv = *(const h8*)(xcL + (m + wf) * XCS + c0);
                    h8 av = *(const h8*)(aL + m * ALS + c0);
                    h8 af = xv * av;
#pragma unroll
                    for (int i = 0; i < 4; i++) acc[mt][i] = MFMA16(af, bA[i], acc[mt][i]);
                }
            }
            {   // odd kk: c0 = 32 + quad*8
                const int c0 = 32 + quad * 8;
#pragma unroll
                for (int mt = 0; mt < 2; mt++) {
                    int m = mg * 32 + mt * 16 + rl;
                    h8 xv = *(const h8*)(xcL + (m + wf) * XCS + c0);
                    h8 av = *(const h8*)(aL + m * ALS + c0);
                    h8 af = xv * av;
#pragma unroll
                    for (int i = 0; i < 4; i++) acc[mt][i] = MFMA16(af, bB[i], acc[mt][i]);
                }
            }
#pragma unroll
            for (int i = 0; i < 4; i++) { bA[i] = bC[i]; bB[i] = bD[i]; }
        }
#pragma unroll
        for (int i = 0; i < 4; i++) {
            int n = ng * 64 + i * 16 + rl;
            float bb = b1[n];
#pragma unroll
            for (int mt = 0; mt < 2; mt++)
#pragma unroll
                for (int r = 0; r < 4; r++) {
                    int m = mg * 32 + mt * 16 + quad * 4 + r;
                    y1L[m * Y1S + n] = to_h(fmaxf(acc[mt][i][r] + bb, 0.f));
                }
        }
    }
    __syncthreads();

    // ---- phase 3: h2 = relu(y1 @ w2 + b2) (M=64 K=256 N=128), kept in regs ----
    f4 acc2[2][2];
#pragma unroll
    for (int mt = 0; mt < 2; mt++)
#pragma unroll
        for (int j = 0; j < 2; j++)
#pragma unroll
            for (int r = 0; r < 4; r++) acc2[mt][j][r] = 0.f;
    {
        const h8* w2v = (const h8*)w2p;
        const int fb2 = nq * 2;
        h8 c0f = w2v[(fb2 + 0) * 64 + lane];
        h8 c1f = w2v[(fb2 + 1) * 64 + lane];
#pragma unroll 2
        for (int kk = 0; kk < 8; kk++) {
            int kn = (kk + 1) & 7;
            h8 n0 = w2v[(kn * 8 + fb2 + 0) * 64 + lane];
            h8 n1 = w2v[(kn * 8 + fb2 + 1) * 64 + lane];
#pragma unroll
            for (int mt = 0; mt < 2; mt++) {
                h8 av = *(const h8*)(y1L + (mg * 32 + mt * 16 + rl) * Y1S + kk * 32 + quad * 8);
                acc2[mt][0] = MFMA16(av, c0f, acc2[mt][0]);
                acc2[mt][1] = MFMA16(av, c1f, acc2[mt][1]);
            }
            c0f = n0; c1f = n1;
        }
    }

    // ---- phase 4: h_short = relu((a .* window[-8:]) @ sw + sb) (K=512 N=128) ----
    f4 accS[2][2];
#pragma unroll
    for (int mt = 0; mt < 2; mt++)
#pragma unroll
        for (int j = 0; j < 2; j++)
#pragma unroll
            for (int r = 0; r < 4; r++) accS[mt][j][r] = 0.f;
    {
        const h8* swv = (const h8*)swp;
        const int fb2 = nq * 2;
        h8 c0f = swv[(fb2 + 0) * 64 + lane];
        h8 c1f = swv[(fb2 + 1) * 64 + lane];
#pragma unroll 2
        for (int kk = 0; kk < 16; kk++) {
            int kn = (kk + 1) & 15;
            h8 n0 = swv[(kn * 8 + fb2 + 0) * 64 + lane];
            h8 n1 = swv[(kn * 8 + fb2 + 1) * 64 + lane];
            const int wf = 24 + (kk >> 1);
            const int c0 = ((kk & 1) << 5) + quad * 8;
#pragma unroll
            for (int mt = 0; mt < 2; mt++) {
                int m = mg * 32 + mt * 16 + rl;
                h8 xv = *(const h8*)(xcL + (m + wf) * XCS + c0);
                h8 av2 = *(const h8*)(aL + m * ALS + c0);
                h8 af = xv * av2;
                accS[mt][0] = MFMA16(af, c0f, accS[mt][0]);
                accS[mt][1] = MFMA16(af, c1f, accS[mt][1]);
            }
            c0f = n0; c1f = n1;
        }
    }
    __syncthreads();  // phase-3 reads of y1L done before overwrite

    // ---- phase 5a: hL[m][0:128]=relu(h2), hL[m][128:256]=relu(h_short) ----
    {
#pragma unroll
        for (int j = 0; j < 2; j++) {
            int n = nq * 32 + j * 16 + rl;
            float bb2 = b2[n], bbs = sb[n];
#pragma unroll
            for (int mt = 0; mt < 2; mt++)
#pragma unroll
                for (int r = 0; r < 4; r++) {
                    int m = mg * 32 + mt * 16 + quad * 4 + r;
                    y1L[m * Y1S + n]       = to_h(fmaxf(acc2[mt][j][r] + bb2, 0.f));
                    y1L[m * Y1S + 128 + n] = to_h(fmaxf(accS[mt][j][r] + bbs, 0.f));
                }
        }
    }
    __syncthreads();

    // ---- phase 5b: out = sigmoid(h @ wo + bo), 128 threads, direct dot ----
    if (tid < 128) {
        int m = tid >> 1, o = tid & 1;
        float z = bo[o];
        const half_t* hrow = y1L + m * Y1S;
        for (int nb = 0; nb < 32; nb++) {
            h8 hv = *(const h8*)(hrow + nb * 8);
#pragma unroll
            for (int j = 0; j < 8; j++)
                z += (float)hv[j] * woL[(nb * 8 + j) * 2 + o];
        }
        z = fminf(fmaxf(z, -30.f), 30.f);
        float sg = 1.f / (1.f + __expf(-z));
        out[((size_t)(b * 4096 + t0 + m)) * 2 + o] = sg;
    }
}

extern "C" void kernel_launch(void* const* d_in, const int* in_sizes, int n_in,
                              void* d_out, int out_size, void* d_ws, size_t ws_size,
                              hipStream_t stream) {
    const float* x      = (const float*)d_in[0];
    const float* conv_w = (const float*)d_in[1];
    const float* conv_b = (const float*)d_in[2];
    const float* se_w1  = (const float*)d_in[3];
    const float* se_b1  = (const float*)d_in[4];
    const float* se_w2  = (const float*)d_in[5];
    const float* se_b2  = (const float*)d_in[6];
    const float* w1     = (const float*)d_in[7];
    const float* b1     = (const float*)d_in[8];
    const float* w2     = (const float*)d_in[9];
    const float* b2     = (const float*)d_in[10];
    const float* sw     = (const float*)d_in[11];
    const float* sb     = (const float*)d_in[12];
    const float* wo     = (const float*)d_in[13];
    const float* bo     = (const float*)d_in[14];
    half_t* wsH = (half_t*)d_ws;

    hipLaunchKernelGGL(pack_k, dim3(337), dim3(256), 0, stream, w1, w2, sw, conv_w, wsH);
    hipLaunchKernelGGL(beat_main, dim3(512), dim3(512), 0, stream,
                       x, conv_b, se_w1, se_b1, se_w2, se_b2, b1, b2, sb, wo, bo,
                       wsH, wsH + 524288, wsH + 557056, wsH + 622592,
                       (float*)d_out);
}